// Round 11
// baseline (174.855 us; speedup 1.0000x reference)
//
#include <hip/hip_runtime.h>

typedef __bf16 bf16;
typedef short s16x8 __attribute__((ext_vector_type(8)));   // 8 bf16 bit-patterns for MFMA frags
typedef __bf16 b16x8 __attribute__((ext_vector_type(8)));  // 8 bf16 for scalar convert paths
typedef float f32x4 __attribute__((ext_vector_type(4)));

#define B_   4096
#define L_   50
#define SH   72               // H row stride (bf16): 64 + 8 pad (2-way bank alias, free)

// ws layout, bf16 elems. Frag-major matrices: frag f = kt*4+nt is a contiguous
// 512-elem (1 KB) block; elem = f*512 + lane*8 + j -> W[k=kt*32+(lane>>4)*8+j][n=nt*16+(lane&15)].
#define OFF_W1F  0            // gv_w1  frag-major, K=128 (16 frags)
#define OFF_W2F  8192         // gv_w2  frag-major, K=64  (8 frags)
#define OFF_W3F  12288        // gv_w3  frag-major
#define OFF_WCF  16384        // (gv_w3 @ att_w1_top) frag-major
#define OFF_A2F  20480        // att_w2 frag-major
#define OFF_R1T  24576        // [64][128] wr1^T row-major (combine tail per-lane dots)
#define OFF_R2T  32768        // [64][64]  wr2^T row-major
#define WT_TOTAL 36864
// byte offsets in ws:
#define BIAS1P_BYTE 73728     // float[64]        att_b1 + gv_b3 @ att_w1_top
#define CQ_BYTE     73984     // float[4096][64]  q_b @ A1_bot  (bias1p added in dense)

#define PREP_W_BLOCKS 145     // ceil((WT_TOTAL+64)/256)
#define PREP_C_BLOCKS 1024    // 4096*64/256

__device__ __forceinline__ unsigned short f2b(float f) {
    __bf16 h = (__bf16)f;
    return __builtin_bit_cast(unsigned short, h);
}
__device__ __forceinline__ unsigned pack2(float a, float b) {
    return (unsigned)f2b(a) | ((unsigned)f2b(b) << 16);
}
__device__ __forceinline__ s16x8 mkfrag(float4 a, float4 b) {
    union { s16x8 v; unsigned u[4]; } r;
    r.u[0] = pack2(a.x, a.y); r.u[1] = pack2(a.z, a.w);
    r.u[2] = pack2(b.x, b.y); r.u[3] = pack2(b.z, b.w);
    return r.v;
}
__device__ __forceinline__ f32x4 mfma16(s16x8 a, s16x8 b, f32x4 c) {
    return __builtin_amdgcn_mfma_f32_16x16x32_bf16(a, b, c, 0, 0, 0);
}

// ---------------- prep (single launch): frag-major weights + bias1' + per-item cq ----------------
extern "C" __global__ void prep_all(const float* __restrict__ w1, const float* __restrict__ w2,
                                    const float* __restrict__ w3, const float* __restrict__ a1,
                                    const float* __restrict__ a2, const float* __restrict__ r1,
                                    const float* __restrict__ r2, const float* __restrict__ gb3,
                                    const float* __restrict__ ab1,
                                    const int* __restrict__ nodes_v, const float* __restrict__ embed_i,
                                    bf16* __restrict__ wt, float* __restrict__ bias1p,
                                    float* __restrict__ cq)
{
    if (blockIdx.x >= PREP_W_BLOCKS) {
        // cq[b][n] = q_b @ A1_bot   (bias1p added in dense)
        int gid = (blockIdx.x - PREP_W_BLOCKS) * 256 + threadIdx.x;   // 4096*64
        int b = gid >> 6, n = gid & 63;
        int v = nodes_v[b];
        const float* q = embed_i + v * 64;
        float s0 = 0.f, s1 = 0.f, s2 = 0.f, s3 = 0.f;
#pragma unroll
        for (int k = 0; k < 64; k += 4) {
            s0 = fmaf(q[k],     a1[(64 + k) * 64 + n],     s0);
            s1 = fmaf(q[k + 1], a1[(64 + k + 1) * 64 + n], s1);
            s2 = fmaf(q[k + 2], a1[(64 + k + 2) * 64 + n], s2);
            s3 = fmaf(q[k + 3], a1[(64 + k + 3) * 64 + n], s3);
        }
        cq[gid] = (s0 + s1) + (s2 + s3);
        return;
    }
    int i = blockIdx.x * 256 + threadIdx.x;
    if (i >= WT_TOTAL + 64) return;
    if (i >= WT_TOTAL) {                       // bias1'[n] = ab1[n] + sum_t gb3[t]*a1[t][n]
        int n = i - WT_TOTAL;
        float s0 = ab1[n], s1 = 0.f, s2 = 0.f, s3 = 0.f;
#pragma unroll
        for (int t = 0; t < 64; t += 4) {
            s0 = fmaf(gb3[t],     a1[t * 64 + n],       s0);
            s1 = fmaf(gb3[t + 1], a1[(t + 1) * 64 + n], s1);
            s2 = fmaf(gb3[t + 2], a1[(t + 2) * 64 + n], s2);
            s3 = fmaf(gb3[t + 3], a1[(t + 3) * 64 + n], s3);
        }
        bias1p[n] = (s0 + s1) + (s2 + s3);
        return;
    }
    float val;
    if (i < OFF_R1T) {
        int off, kind;   // 0=w1,1=w2,2=w3,3=wca,4=a2
        if      (i < OFF_W2F) { off = OFF_W1F; kind = 0; }
        else if (i < OFF_W3F) { off = OFF_W2F; kind = 1; }
        else if (i < OFF_WCF) { off = OFF_W3F; kind = 2; }
        else if (i < OFF_A2F) { off = OFF_WCF; kind = 3; }
        else                  { off = OFF_A2F; kind = 4; }
        int local = i - off;
        int f = local >> 9, lane = (local >> 3) & 63, j = local & 7;
        int kt = f >> 2, nt = f & 3, quad = lane >> 4, m = lane & 15;
        int k = kt * 32 + quad * 8 + j;
        int n = nt * 16 + m;
        if (kind == 0)      val = w1[k * 64 + n];
        else if (kind == 1) val = w2[k * 64 + n];
        else if (kind == 2) val = w3[k * 64 + n];
        else if (kind == 4) val = a2[k * 64 + n];
        else {                                  // wca[k][n] = (W3 @ A1_top)[k][n]
            float s0 = 0.f, s1 = 0.f, s2 = 0.f, s3 = 0.f;
#pragma unroll
            for (int t = 0; t < 64; t += 4) {
                float4 w = *(const float4*)(w3 + k * 64 + t);
                s0 = fmaf(w.x, a1[t * 64 + n],       s0);
                s1 = fmaf(w.y, a1[(t + 1) * 64 + n], s1);
                s2 = fmaf(w.z, a1[(t + 2) * 64 + n], s2);
                s3 = fmaf(w.w, a1[(t + 3) * 64 + n], s3);
            }
            val = (s0 + s1) + (s2 + s3);
        }
    }
    else if (i < OFF_R2T) { int li = i - OFF_R1T; int n = li >> 7, k = li & 127; val = r1[k * 64 + n]; }
    else                  { int li = i - OFF_R2T; int n = li >> 6, k = li & 63;  val = r2[k * 64 + n]; }
    wt[i] = (bf16)val;
}

// ---------------- fused: 1 item x 64 padded rows per block, single-tile waves ----------------
// 4096 blocks x 4 waves; wave w owns rows [16w,16w+16). Halved per-wave accumulator footprint
// (vs dual-tile) -> ~5-6 waves/SIMD residency; halved per-wave serial chain.
extern "C" __global__ void __launch_bounds__(256, 2)
dense_fused(const int* __restrict__ nodes_v, const int* __restrict__ neigh_u,
            const int* __restrict__ neigh_r,
            const float* __restrict__ embed_u, const float* __restrict__ embed_i,
            const float* __restrict__ embed_r,
            const float* __restrict__ gv_b1, const float* __restrict__ gv_b2,
            const float* __restrict__ gv_b3,
            const float* __restrict__ att_b2, const float* __restrict__ att_w3,
            const float* __restrict__ wr1_b, const float* __restrict__ wr2_b,
            const bf16* __restrict__ wt, const float* __restrict__ cq,
            const float* __restrict__ bias1p, float* __restrict__ out)
{
    __shared__ __align__(16) bf16 H[64 * SH];       // 9216 B: h1 -> h2 -> att1h (same-wave reuse)
    __shared__ float csS[64];                       // att1 per-item bias
    __shared__ float qsh[64];                       // q
    __shared__ float scs[64];                       // scores; reused as zj-share in tail
    __shared__ float zp[4 * 64];                    // zj partials per wave

    const int tid = threadIdx.x;
    const int lane = tid & 63, wave = tid >> 6;
    const int m = lane & 15, quad = lane >> 4;
    const int b = blockIdx.x;

    // stage per-item att1 bias (cq + bias1p) and q (visible after barrier 1)
    if (tid < 64)        csS[tid] = cq[b * 64 + tid] + bias1p[tid];
    else if (tid < 128)  qsh[tid - 64] = embed_i[nodes_v[b] * 64 + (tid - 64)];

    // this lane's neighbor row (clamped; pad rows masked at softmax)
    const int l = min(wave * 16 + m, L_ - 1);
    const int u = neigh_u[b * L_ + l];
    const int r = neigh_r[b * L_ + l];

    bf16* Hw = H + wave * 16 * SH;   // this wave's 16 rows

    // ---- gv1 straight from global regs: h1 = relu([pt|er] @ W1 + b1) -> H ----
    {
        const float* pu = embed_u + u * 64;   // kt 0,1
        const float* pr = embed_r + r * 64;   // kt 2,3
        f32x4 ac[4] = {};
#pragma unroll
        for (int kt = 0; kt < 4; ++kt) {
            const float* sp = (kt < 2 ? pu : pr) + (kt & 1) * 32 + quad * 8;
            float4 aa = *(const float4*)sp, ab = *(const float4*)(sp + 4);
            s16x8 af = mkfrag(aa, ab);
#pragma unroll
            for (int nt = 0; nt < 4; ++nt) {
                s16x8 bw = *(const s16x8*)(wt + OFF_W1F + (kt * 4 + nt) * 512 + lane * 8);
                ac[nt] = mfma16(af, bw, ac[nt]);
            }
        }
#pragma unroll
        for (int nt = 0; nt < 4; ++nt) {
            int c = nt * 16 + m;
            float bv = gv_b1[c];
#pragma unroll
            for (int r4 = 0; r4 < 4; ++r4)
                Hw[(quad * 4 + r4) * SH + c] = (bf16)fmaxf(ac[nt][r4] + bv, 0.f);
        }
    }

    // ---- gv2: h1 -> h2 (in-place, same-wave WAR safe) ----
    {
        f32x4 ac[4] = {};
#pragma unroll
        for (int kt = 0; kt < 2; ++kt) {
            s16x8 a = *(const s16x8*)(Hw + m * SH + kt * 32 + quad * 8);
#pragma unroll
            for (int nt = 0; nt < 4; ++nt) {
                s16x8 bw = *(const s16x8*)(wt + OFF_W2F + (kt * 4 + nt) * 512 + lane * 8);
                ac[nt] = mfma16(a, bw, ac[nt]);
            }
        }
#pragma unroll
        for (int nt = 0; nt < 4; ++nt) {
            int c = nt * 16 + m;
            float bv = gv_b2[c];
#pragma unroll
            for (int r4 = 0; r4 < 4; ++r4)
                Hw[(quad * 4 + r4) * SH + c] = (bf16)fmaxf(ac[nt][r4] + bv, 0.f);
        }
    }

    __syncthreads();   // csS/qsh visible

    // ---- fused gv3 + att1': consume h2; fjt stays in regs (aF), att1h -> H ----
    f32x4 aF[4] = {};
    {
        f32x4 aA[4] = {};
#pragma unroll
        for (int kt = 0; kt < 2; ++kt) {
            s16x8 a = *(const s16x8*)(Hw + m * SH + kt * 32 + quad * 8);
#pragma unroll
            for (int nt = 0; nt < 4; ++nt) {
                s16x8 bF = *(const s16x8*)(wt + OFF_W3F + (kt * 4 + nt) * 512 + lane * 8);
                s16x8 bA = *(const s16x8*)(wt + OFF_WCF + (kt * 4 + nt) * 512 + lane * 8);
                aF[nt] = mfma16(a, bF, aF[nt]);
                aA[nt] = mfma16(a, bA, aA[nt]);
            }
        }
        // write only att1h; aF kept in regs (gv_b3 folded into zj via sum(mu)==1)
#pragma unroll
        for (int nt = 0; nt < 4; ++nt) {
            int c = nt * 16 + m;
            float b1v = csS[c];
#pragma unroll
            for (int r4 = 0; r4 < 4; ++r4)
                Hw[(quad * 4 + r4) * SH + c] = (bf16)fmaxf(aA[nt][r4] + b1v, 0.f);
        }
    }

    // ---- att2 + relu + dot(att_w3) + cross-m reduce -> scores (LDS) ----
    {
        f32x4 ac[4] = {};
#pragma unroll
        for (int kt = 0; kt < 2; ++kt) {
            s16x8 a = *(const s16x8*)(Hw + m * SH + kt * 32 + quad * 8);
#pragma unroll
            for (int nt = 0; nt < 4; ++nt) {
                s16x8 bw = *(const s16x8*)(wt + OFF_A2F + (kt * 4 + nt) * 512 + lane * 8);
                ac[nt] = mfma16(a, bw, ac[nt]);
            }
        }
        float sc[4] = {0.f, 0.f, 0.f, 0.f};
#pragma unroll
        for (int nt = 0; nt < 4; ++nt) {
            int c = nt * 16 + m;
            float b2v = att_b2[c], w3v = att_w3[c];
#pragma unroll
            for (int r4 = 0; r4 < 4; ++r4)
                sc[r4] += fmaxf(ac[nt][r4] + b2v, 0.f) * w3v;
        }
#pragma unroll
        for (int mask = 1; mask < 16; mask <<= 1)
#pragma unroll
            for (int r4 = 0; r4 < 4; ++r4) sc[r4] += __shfl_xor(sc[r4], mask);
        if (m == 0) {
#pragma unroll
            for (int r4 = 0; r4 < 4; ++r4)
                scs[wave * 16 + quad * 4 + r4] = sc[r4];
        }
    }
    __syncthreads();   // all 64 scores visible

    // ---- per-wave softmax + zj from aF regs ----
    {
        float s = (lane < L_) ? scs[lane] : -1e30f;
        float mx = s;
#pragma unroll
        for (int off = 32; off; off >>= 1) mx = fmaxf(mx, __shfl_xor(mx, off));
        float e = (lane < L_) ? __expf(s - mx) : 0.f;
        float sum = e;
#pragma unroll
        for (int off = 32; off; off >>= 1) sum += __shfl_xor(sum, off);
        float mu = e / sum;   // mu[lane]

        float z[4] = {0.f, 0.f, 0.f, 0.f};
#pragma unroll
        for (int r4 = 0; r4 < 4; ++r4) {
            float mr = __shfl(mu, wave * 16 + quad * 4 + r4);
#pragma unroll
            for (int nt = 0; nt < 4; ++nt) z[nt] += aF[nt][r4] * mr;
        }
#pragma unroll
        for (int nt = 0; nt < 4; ++nt) {
            z[nt] += __shfl_xor(z[nt], 16);
            z[nt] += __shfl_xor(z[nt], 32);
        }
        if (quad == 0) {
#pragma unroll
            for (int nt = 0; nt < 4; ++nt) zp[wave * 64 + nt * 16 + m] = z[nt];
        }
    }
    __syncthreads();

    // ---- combine tail on wave 0 ----
    if (wave == 0) {
        const int d = lane;
        float z = zp[d] + zp[64 + d] + zp[128 + d] + zp[192 + d] + gv_b3[d];
        scs[d] = z;   // scores dead; reuse (same-wave in-order)

        // z2 = relu([zj|q] @ wr1 + b1)
        float accz = wr1_b[d];
        const bf16* r1 = wt + OFF_R1T + d * 128;
#pragma unroll
        for (int k8 = 0; k8 < 8; ++k8) {
            b16x8 wv = *(const b16x8*)(r1 + k8 * 8);
#pragma unroll
            for (int j = 0; j < 8; ++j) accz = fmaf((float)wv[j], scs[k8 * 8 + j], accz);
        }
#pragma unroll
        for (int k8 = 0; k8 < 8; ++k8) {
            b16x8 wv = *(const b16x8*)(r1 + 64 + k8 * 8);
#pragma unroll
            for (int j = 0; j < 8; ++j) accz = fmaf((float)wv[j], qsh[k8 * 8 + j], accz);
        }
        zp[d] = fmaxf(accz, 0.f);   // reuse as z2-share (same-wave in-order)

        // out = relu(z2 @ wr2 + b2)
        float acco = wr2_b[d];
        const bf16* r2 = wt + OFF_R2T + d * 64;
#pragma unroll
        for (int k8 = 0; k8 < 8; ++k8) {
            b16x8 wv = *(const b16x8*)(r2 + k8 * 8);
#pragma unroll
            for (int j = 0; j < 8; ++j) acco = fmaf((float)wv[j], zp[k8 * 8 + j], acco);
        }
        out[b * 64 + d] = fmaxf(acco, 0.f);
    }
}

extern "C" void kernel_launch(void* const* d_in, const int* in_sizes, int n_in,
                              void* d_out, int out_size, void* d_ws, size_t ws_size,
                              hipStream_t stream)
{
    const int* nodes_v = (const int*)d_in[0];
    const int* neigh_u = (const int*)d_in[1];
    const int* neigh_r = (const int*)d_in[2];
    const float* embed_u = (const float*)d_in[3];
    const float* embed_i = (const float*)d_in[4];
    const float* embed_r = (const float*)d_in[5];
    const float* gv_w1  = (const float*)d_in[6];  const float* gv_b1 = (const float*)d_in[7];
    const float* gv_w2  = (const float*)d_in[8];  const float* gv_b2 = (const float*)d_in[9];
    const float* gv_w3  = (const float*)d_in[10]; const float* gv_b3 = (const float*)d_in[11];
    const float* att_w1 = (const float*)d_in[12]; const float* att_b1 = (const float*)d_in[13];
    const float* att_w2 = (const float*)d_in[14]; const float* att_b2 = (const float*)d_in[15];
    const float* att_w3 = (const float*)d_in[16]; const float* att_b3 = (const float*)d_in[17];
    const float* wr1_w  = (const float*)d_in[18]; const float* wr1_b = (const float*)d_in[19];
    const float* wr2_w  = (const float*)d_in[20]; const float* wr2_b = (const float*)d_in[21];
    (void)att_b3;  // softmax shift-invariance

    bf16*  wt     = (bf16*)d_ws;
    float* bias1p = (float*)((char*)d_ws + BIAS1P_BYTE);
    float* cq     = (float*)((char*)d_ws + CQ_BYTE);

    prep_all<<<PREP_W_BLOCKS + PREP_C_BLOCKS, 256, 0, stream>>>(
        gv_w1, gv_w2, gv_w3, att_w1, att_w2, wr1_w, wr2_w, gv_b3, att_b1,
        nodes_v, embed_i, wt, bias1p, cq);
    dense_fused<<<B_, 256, 0, stream>>>(nodes_v, neigh_u, neigh_r,
                                        embed_u, embed_i, embed_r,
                                        gv_b1, gv_b2, gv_b3, att_b2, att_w3,
                                        wr1_b, wr2_b, wt, cq, bias1p, (float*)d_out);
}

// Round 13
// 168.659 us; speedup vs baseline: 1.0367x; 1.0367x over previous
//
#include <hip/hip_runtime.h>

typedef __bf16 bf16;
typedef short s16x8 __attribute__((ext_vector_type(8)));   // 8 bf16 bit-patterns for MFMA frags
typedef __bf16 b16x8 __attribute__((ext_vector_type(8)));  // 8 bf16 for scalar convert paths
typedef float f32x4 __attribute__((ext_vector_type(4)));

#define B_   4096
#define L_   50
#define SH   72               // H row stride (bf16): 64 + 8 pad (2-way bank alias, free)

// ws layout, bf16 elems. Frag-major matrices: frag f = kt*4+nt is a contiguous
// 512-elem (1 KB) block; elem = f*512 + lane*8 + j -> W[k=kt*32+(lane>>4)*8+j][n=nt*16+(lane&15)].
// W2F/W3F/WCF/A2F (32 KB) are staged to LDS by dense_fused; W1F stays global (L1-hot).
#define OFF_W1F  0            // gv_w1  frag-major, K=128 (16 frags)
#define OFF_W2F  8192         // gv_w2  frag-major, K=64 (8 frags)
#define OFF_W3F  12288        // gv_w3  frag-major
#define OFF_WCF  16384        // (gv_w3 @ att_w1_top) frag-major
#define OFF_A2F  20480        // att_w2 frag-major
#define OFF_R1T  24576        // [64][128] wr1^T row-major (combine tail per-lane dots)
#define OFF_R2T  32768        // [64][64]  wr2^T row-major
#define WT_TOTAL 36864
// byte offsets in ws:
#define BIAS1P_BYTE 73728     // float[64]        att_b1 + gv_b3 @ att_w1_top
#define CQ_BYTE     73984     // float[4096][64]  q_b @ A1_bot  (bias1p added in dense)

#define PREP_W_BLOCKS 145     // ceil((WT_TOTAL+64)/256)
#define PREP_C_BLOCKS 1024    // 4096*64/256

__device__ __forceinline__ unsigned short f2b(float f) {
    __bf16 h = (__bf16)f;
    return __builtin_bit_cast(unsigned short, h);
}
__device__ __forceinline__ unsigned pack2(float a, float b) {
    return (unsigned)f2b(a) | ((unsigned)f2b(b) << 16);
}
__device__ __forceinline__ s16x8 mkfrag(float4 a, float4 b) {
    union { s16x8 v; unsigned u[4]; } r;
    r.u[0] = pack2(a.x, a.y); r.u[1] = pack2(a.z, a.w);
    r.u[2] = pack2(b.x, b.y); r.u[3] = pack2(b.z, b.w);
    return r.v;
}
__device__ __forceinline__ f32x4 mfma16(s16x8 a, s16x8 b, f32x4 c) {
    return __builtin_amdgcn_mfma_f32_16x16x32_bf16(a, b, c, 0, 0, 0);
}

// ---------------- prep (single launch): frag-major weights + bias1' + per-item cq ----------------
extern "C" __global__ void prep_all(const float* __restrict__ w1, const float* __restrict__ w2,
                                    const float* __restrict__ w3, const float* __restrict__ a1,
                                    const float* __restrict__ a2, const float* __restrict__ r1,
                                    const float* __restrict__ r2, const float* __restrict__ gb3,
                                    const float* __restrict__ ab1,
                                    const int* __restrict__ nodes_v, const float* __restrict__ embed_i,
                                    bf16* __restrict__ wt, float* __restrict__ bias1p,
                                    float* __restrict__ cq)
{
    if (blockIdx.x >= PREP_W_BLOCKS) {
        // cq[b][n] = q_b @ A1_bot   (bias1p added in dense)
        int gid = (blockIdx.x - PREP_W_BLOCKS) * 256 + threadIdx.x;   // 4096*64
        int b = gid >> 6, n = gid & 63;
        int v = nodes_v[b];
        const float* q = embed_i + v * 64;
        float s0 = 0.f, s1 = 0.f, s2 = 0.f, s3 = 0.f;
#pragma unroll
        for (int k = 0; k < 64; k += 4) {
            s0 = fmaf(q[k],     a1[(64 + k) * 64 + n],     s0);
            s1 = fmaf(q[k + 1], a1[(64 + k + 1) * 64 + n], s1);
            s2 = fmaf(q[k + 2], a1[(64 + k + 2) * 64 + n], s2);
            s3 = fmaf(q[k + 3], a1[(64 + k + 3) * 64 + n], s3);
        }
        cq[gid] = (s0 + s1) + (s2 + s3);
        return;
    }
    int i = blockIdx.x * 256 + threadIdx.x;
    if (i >= WT_TOTAL + 64) return;
    if (i >= WT_TOTAL) {                       // bias1'[n] = ab1[n] + sum_t gb3[t]*a1[t][n]
        int n = i - WT_TOTAL;
        float s0 = ab1[n], s1 = 0.f, s2 = 0.f, s3 = 0.f;
#pragma unroll
        for (int t = 0; t < 64; t += 4) {
            s0 = fmaf(gb3[t],     a1[t * 64 + n],       s0);
            s1 = fmaf(gb3[t + 1], a1[(t + 1) * 64 + n], s1);
            s2 = fmaf(gb3[t + 2], a1[(t + 2) * 64 + n], s2);
            s3 = fmaf(gb3[t + 3], a1[(t + 3) * 64 + n], s3);
        }
        bias1p[n] = (s0 + s1) + (s2 + s3);
        return;
    }
    float val;
    if (i < OFF_R1T) {
        int off, kind;   // 0=w1,1=w2,2=w3,3=wca,4=a2
        if      (i < OFF_W2F) { off = OFF_W1F; kind = 0; }
        else if (i < OFF_W3F) { off = OFF_W2F; kind = 1; }
        else if (i < OFF_WCF) { off = OFF_W3F; kind = 2; }
        else if (i < OFF_A2F) { off = OFF_WCF; kind = 3; }
        else                  { off = OFF_A2F; kind = 4; }
        int local = i - off;
        int f = local >> 9, lane = (local >> 3) & 63, j = local & 7;
        int kt = f >> 2, nt = f & 3, quad = lane >> 4, m = lane & 15;
        int k = kt * 32 + quad * 8 + j;
        int n = nt * 16 + m;
        if (kind == 0)      val = w1[k * 64 + n];
        else if (kind == 1) val = w2[k * 64 + n];
        else if (kind == 2) val = w3[k * 64 + n];
        else if (kind == 4) val = a2[k * 64 + n];
        else {                                  // wca[k][n] = (W3 @ A1_top)[k][n]
            float s0 = 0.f, s1 = 0.f, s2 = 0.f, s3 = 0.f;
#pragma unroll
            for (int t = 0; t < 64; t += 4) {
                float4 w = *(const float4*)(w3 + k * 64 + t);
                s0 = fmaf(w.x, a1[t * 64 + n],       s0);
                s1 = fmaf(w.y, a1[(t + 1) * 64 + n], s1);
                s2 = fmaf(w.z, a1[(t + 2) * 64 + n], s2);
                s3 = fmaf(w.w, a1[(t + 3) * 64 + n], s3);
            }
            val = (s0 + s1) + (s2 + s3);
        }
    }
    else if (i < OFF_R2T) { int li = i - OFF_R1T; int n = li >> 7, k = li & 127; val = r1[k * 64 + n]; }
    else                  { int li = i - OFF_R2T; int n = li >> 6, k = li & 63;  val = r2[k * 64 + n]; }
    wt[i] = (bf16)val;
}

// ---------------- fused: 2 items x 64 padded rows/block; K=64 weights in LDS frag-major ----------------
// 2048 blocks x 4 waves, dual 16-row tiles (B-frags shared across tiles). W1 from global (L1-hot,
// working set now 28 KB < 32 KB L1); w2/w3/wca/a2 staged to LDS (conflict-free lane*16B reads).
extern "C" __global__ void __launch_bounds__(256, 2)
dense_fused(const int* __restrict__ nodes_v, const int* __restrict__ neigh_u,
            const int* __restrict__ neigh_r,
            const float* __restrict__ embed_u, const float* __restrict__ embed_i,
            const float* __restrict__ embed_r,
            const float* __restrict__ gv_b1, const float* __restrict__ gv_b2,
            const float* __restrict__ gv_b3,
            const float* __restrict__ att_b2, const float* __restrict__ att_w3,
            const float* __restrict__ wr1_b, const float* __restrict__ wr2_b,
            const bf16* __restrict__ wt, const float* __restrict__ cq,
            const float* __restrict__ bias1p, float* __restrict__ out)
{
    __shared__ __align__(16) bf16 Ws[16384];        // 32 KB: W2F|W3F|WCF|A2F frag-major
    __shared__ __align__(16) bf16 H[128 * SH];      // 18.4 KB: h1 -> h2 -> att1h (same-wave reuse)
    __shared__ float csS[128];                      // att1 bias per item (2 x 64)
    __shared__ float qsh[128];                      // q per item
    __shared__ float scs[128];                      // scores; reused as zj-share in tail
    __shared__ float zp[4 * 64];                    // zj partials per wave

    const int tid = threadIdx.x;
    const int lane = tid & 63, wave = tid >> 6;
    const int m = lane & 15, quad = lane >> 4;
    const int b0 = blockIdx.x * 2;
    const int rw0 = wave * 32;                      // wave's rows in [0,128)
    const int item_w = rw0 >> 6;                    // this wave's item (0/1)
    const int lbase = rw0 & 63;                     // neighbor offset within item (0/32)

    // ---- stage K=64 weights -> LDS (coalesced b128; latency hidden behind gather+gv1) ----
    {
        const uint4* src = (const uint4*)(wt + OFF_W2F);   // 16384 elems = 2048 uint4
        uint4* dst = (uint4*)Ws;
#pragma unroll
        for (int it = 0; it < 8; ++it) dst[tid + it * 256] = src[tid + it * 256];
    }
    // stage per-item att1 bias (cq + bias1p) and q
    if (tid < 128) {
        int item = tid >> 6, n = tid & 63;
        csS[tid] = cq[(b0 + item) * 64 + n] + bias1p[n];
        qsh[tid] = embed_i[nodes_v[b0 + item] * 64 + n];
    }

    // neighbor indices for this lane's two A-frag rows (clamped; pad rows masked at softmax)
    const int bw = b0 + item_w;
    const int l0 = min(lbase + m, L_ - 1);
    const int l1 = min(lbase + 16 + m, L_ - 1);
    const int u0 = neigh_u[bw * L_ + l0], u1 = neigh_u[bw * L_ + l1];
    const int v0 = neigh_r[bw * L_ + l0], v1 = neigh_r[bw * L_ + l1];

    bf16* Hw = H + rw0 * SH;   // this wave's 32 rows
    bf16* H0 = Hw;             // tile 0
    bf16* H1 = Hw + 16 * SH;   // tile 1

    // ---- gv1 straight from global regs: h1 = relu([pt|er] @ W1 + b1) -> H (W1 from L1) ----
    {
        const float* b00 = embed_u + u0 * 64;   // kt 0,1: pt
        const float* b01 = embed_u + u1 * 64;
        const float* b10 = embed_r + v0 * 64;   // kt 2,3: er
        const float* b11 = embed_r + v1 * 64;
        f32x4 ac0[4] = {}, ac1[4] = {};
#pragma unroll
        for (int kt = 0; kt < 4; ++kt) {
            const float* s0p = (kt < 2 ? b00 : b10) + (kt & 1) * 32 + quad * 8;
            const float* s1p = (kt < 2 ? b01 : b11) + (kt & 1) * 32 + quad * 8;
            float4 a0a = *(const float4*)s0p, a0b = *(const float4*)(s0p + 4);
            float4 a1a = *(const float4*)s1p, a1b = *(const float4*)(s1p + 4);
            s16x8 a0 = mkfrag(a0a, a0b);
            s16x8 a1 = mkfrag(a1a, a1b);
#pragma unroll
            for (int nt = 0; nt < 4; ++nt) {
                s16x8 b = *(const s16x8*)(wt + OFF_W1F + (kt * 4 + nt) * 512 + lane * 8);
                ac0[nt] = mfma16(a0, b, ac0[nt]);
                ac1[nt] = mfma16(a1, b, ac1[nt]);
            }
        }
#pragma unroll
        for (int nt = 0; nt < 4; ++nt) {
            int c = nt * 16 + m;
            float bv = gv_b1[c];
#pragma unroll
            for (int r4 = 0; r4 < 4; ++r4) {
                H0[(quad * 4 + r4) * SH + c] = (bf16)fmaxf(ac0[nt][r4] + bv, 0.f);
                H1[(quad * 4 + r4) * SH + c] = (bf16)fmaxf(ac1[nt][r4] + bv, 0.f);
            }
        }
    }

    __syncthreads();   // Ws + csS + qsh ready

    // ---- gv2: h1 -> h2 (in-place, same-wave WAR safe; B-frags from LDS) ----
    {
        f32x4 ac0[4] = {}, ac1[4] = {};
#pragma unroll
        for (int kt = 0; kt < 2; ++kt) {
            s16x8 a0 = *(const s16x8*)(H0 + m * SH + kt * 32 + quad * 8);
            s16x8 a1 = *(const s16x8*)(H1 + m * SH + kt * 32 + quad * 8);
#pragma unroll
            for (int nt = 0; nt < 4; ++nt) {
                s16x8 b = *(const s16x8*)(Ws + (kt * 4 + nt) * 512 + lane * 8);   // W2F
                ac0[nt] = mfma16(a0, b, ac0[nt]);
                ac1[nt] = mfma16(a1, b, ac1[nt]);
            }
        }
#pragma unroll
        for (int nt = 0; nt < 4; ++nt) {
            int c = nt * 16 + m;
            float bv = gv_b2[c];
#pragma unroll
            for (int r4 = 0; r4 < 4; ++r4) {
                H0[(quad * 4 + r4) * SH + c] = (bf16)fmaxf(ac0[nt][r4] + bv, 0.f);
                H1[(quad * 4 + r4) * SH + c] = (bf16)fmaxf(ac1[nt][r4] + bv, 0.f);
            }
        }
    }

    // ---- fused gv3 + att1': consume h2; fjt stays in regs (aF), att1h -> H ----
    f32x4 aF0[4] = {}, aF1[4] = {};
    {
        f32x4 aA0[4] = {}, aA1[4] = {};
#pragma unroll
        for (int kt = 0; kt < 2; ++kt) {
            s16x8 a0 = *(const s16x8*)(H0 + m * SH + kt * 32 + quad * 8);
            s16x8 a1 = *(const s16x8*)(H1 + m * SH + kt * 32 + quad * 8);
#pragma unroll
            for (int nt = 0; nt < 4; ++nt) {
                s16x8 bF = *(const s16x8*)(Ws + 4096 + (kt * 4 + nt) * 512 + lane * 8);  // W3F
                s16x8 bA = *(const s16x8*)(Ws + 8192 + (kt * 4 + nt) * 512 + lane * 8);  // WCF
                aF0[nt] = mfma16(a0, bF, aF0[nt]);
                aF1[nt] = mfma16(a1, bF, aF1[nt]);
                aA0[nt] = mfma16(a0, bA, aA0[nt]);
                aA1[nt] = mfma16(a1, bA, aA1[nt]);
            }
        }
        // write only att1h; aF kept in regs (gv_b3 folded into zj via sum(mu)==1)
#pragma unroll
        for (int nt = 0; nt < 4; ++nt) {
            int c = nt * 16 + m;
            float b1v = csS[item_w * 64 + c];
#pragma unroll
            for (int r4 = 0; r4 < 4; ++r4) {
                H0[(quad * 4 + r4) * SH + c] = (bf16)fmaxf(aA0[nt][r4] + b1v, 0.f);
                H1[(quad * 4 + r4) * SH + c] = (bf16)fmaxf(aA1[nt][r4] + b1v, 0.f);
            }
        }
    }

    // ---- att2 + relu + dot(att_w3) + quad-reduce -> scores (LDS) ----
    {
        f32x4 ac0[4] = {}, ac1[4] = {};
#pragma unroll
        for (int kt = 0; kt < 2; ++kt) {
            s16x8 a0 = *(const s16x8*)(H0 + m * SH + kt * 32 + quad * 8);
            s16x8 a1 = *(const s16x8*)(H1 + m * SH + kt * 32 + quad * 8);
#pragma unroll
            for (int nt = 0; nt < 4; ++nt) {
                s16x8 b = *(const s16x8*)(Ws + 12288 + (kt * 4 + nt) * 512 + lane * 8);  // A2F
                ac0[nt] = mfma16(a0, b, ac0[nt]);
                ac1[nt] = mfma16(a1, b, ac1[nt]);
            }
        }
        float s0[4] = {0.f, 0.f, 0.f, 0.f}, s1[4] = {0.f, 0.f, 0.f, 0.f};
#pragma unroll
        for (int nt = 0; nt < 4; ++nt) {
            int c = nt * 16 + m;
            float b2v = att_b2[c], w3v = att_w3[c];
#pragma unroll
            for (int r4 = 0; r4 < 4; ++r4) {
                s0[r4] += fmaxf(ac0[nt][r4] + b2v, 0.f) * w3v;
                s1[r4] += fmaxf(ac1[nt][r4] + b2v, 0.f) * w3v;
            }
        }
#pragma unroll
        for (int mask = 1; mask < 16; mask <<= 1)
#pragma unroll
            for (int r4 = 0; r4 < 4; ++r4) {
                s0[r4] += __shfl_xor(s0[r4], mask);
                s1[r4] += __shfl_xor(s1[r4], mask);
            }
        if (m == 0) {
#pragma unroll
            for (int r4 = 0; r4 < 4; ++r4) {
                scs[item_w * 64 + lbase + quad * 4 + r4] = s0[r4];
                scs[item_w * 64 + lbase + 16 + quad * 4 + r4] = s1[r4];
            }
        }
    }
    __syncthreads();   // all 64 scores of each item visible

    // ---- per-wave softmax + zj from aF regs (fjt never in LDS) ----
    {
        float s = (lane < L_) ? scs[item_w * 64 + lane] : -1e30f;
        float mx = s;
#pragma unroll
        for (int off = 32; off; off >>= 1) mx = fmaxf(mx, __shfl_xor(mx, off));
        float e = (lane < L_) ? __expf(s - mx) : 0.f;
        float sum = e;
#pragma unroll
        for (int off = 32; off; off >>= 1) sum += __shfl_xor(sum, off);
        float mu = e / sum;   // mu[lane] of this wave's item

        float z[4] = {0.f, 0.f, 0.f, 0.f};
#pragma unroll
        for (int r4 = 0; r4 < 4; ++r4) {
            float m0 = __shfl(mu, lbase + quad * 4 + r4);
            float m1 = __shfl(mu, lbase + 16 + quad * 4 + r4);
#pragma unroll
            for (int nt = 0; nt < 4; ++nt)
                z[nt] += aF0[nt][r4] * m0 + aF1[nt][r4] * m1;
        }
#pragma unroll
        for (int nt = 0; nt < 4; ++nt) {
            z[nt] += __shfl_xor(z[nt], 16);
            z[nt] += __shfl_xor(z[nt], 32);
        }
        if (quad == 0) {
#pragma unroll
            for (int nt = 0; nt < 4; ++nt) zp[wave * 64 + nt * 16 + m] = z[nt];
        }
    }
    __syncthreads();

    // ---- combine tail: wave 0 -> item 0, wave 2 -> item 1 ----
    if ((wave & 1) == 0) {
        const int item = wave >> 1;
        const int d = lane;
        float z = zp[wave * 64 + d] + zp[wave * 64 + 64 + d] + gv_b3[d];
        float* zsh = scs + item * 64;   // scores dead; reuse (same-wave in-order)
        zsh[d] = z;

        // z2 = relu([zj|q] @ wr1 + b1)
        float accz = wr1_b[d];
        const bf16* r1 = wt + OFF_R1T + d * 128;
#pragma unroll
        for (int k8 = 0; k8 < 8; ++k8) {
            b16x8 wv = *(const b16x8*)(r1 + k8 * 8);
#pragma unroll
            for (int j = 0; j < 8; ++j) accz = fmaf((float)wv[j], zsh[k8 * 8 + j], accz);
        }
#pragma unroll
        for (int k8 = 0; k8 < 8; ++k8) {
            b16x8 wv = *(const b16x8*)(r1 + 64 + k8 * 8);
#pragma unroll
            for (int j = 0; j < 8; ++j) accz = fmaf((float)wv[j], qsh[item * 64 + k8 * 8 + j], accz);
        }
        float* z2sh = zp + wave * 64;   // reuse own partial slot (same-wave in-order)
        z2sh[d] = fmaxf(accz, 0.f);

        // out = relu(z2 @ wr2 + b2)
        float acco = wr2_b[d];
        const bf16* r2 = wt + OFF_R2T + d * 64;
#pragma unroll
        for (int k8 = 0; k8 < 8; ++k8) {
            b16x8 wv = *(const b16x8*)(r2 + k8 * 8);
#pragma unroll
            for (int j = 0; j < 8; ++j) acco = fmaf((float)wv[j], z2sh[k8 * 8 + j], acco);
        }
        out[(b0 + item) * 64 + d] = fmaxf(acco, 0.f);
    }
}

extern "C" void kernel_launch(void* const* d_in, const int* in_sizes, int n_in,
                              void* d_out, int out_size, void* d_ws, size_t ws_size,
                              hipStream_t stream)
{
    const int* nodes_v = (const int*)d_in[0];
    const int* neigh_u = (const int*)d_in[1];
    const int* neigh_r = (const int*)d_in[2];
    const float* embed_u = (const float*)d_in[3];
    const float* embed_i = (const float*)d_in[4];
    const float* embed_r = (const float*)d_in[5];
    const float* gv_w1  = (const float*)d_in[6];  const float* gv_b1 = (const float*)d_in[7];
    const float* gv_w2  = (const float*)d_in[8];  const float* gv_b2 = (const float*)d_in[9];
    const float* gv_w3  = (const float*)d_in[10]; const float* gv_b3 = (const float*)d_in[11];
    const float* att_w1 = (const float*)d_in[12]; const float* att_b1 = (const float*)d_in[13];
    const float* att_w2 = (const float*)d_in[14]; const float* att_b2 = (const float*)d_in[15];
    const float* att_w3 = (const float*)d_in[16]; const float* att_b3 = (const float*)d_in[17];
    const float* wr1_w  = (const float*)d_in[18]; const float* wr1_b = (const float*)d_in[19];
    const float* wr2_w  = (const float*)d_in[20]; const float* wr2_b = (const float*)d_in[21];
    (void)att_b3;  // softmax shift-invariance

    bf16*  wt     = (bf16*)d_ws;
    float* bias1p = (float*)((char*)d_ws + BIAS1P_BYTE);
    float* cq     = (float*)((char*)d_ws + CQ_BYTE);

    prep_all<<<PREP_W_BLOCKS + PREP_C_BLOCKS, 256, 0, stream>>>(
        gv_w1, gv_w2, gv_w3, att_w1, att_w2, wr1_w, wr2_w, gv_b3, att_b1,
        nodes_v, embed_i, wt, bias1p, cq);
    dense_fused<<<B_ / 2, 256, 0, stream>>>(nodes_v, neigh_u, neigh_r,
                                            embed_u, embed_i, embed_r,
                                            gv_b1, gv_b2, gv_b3, att_b2, att_w3,
                                            wr1_b, wr2_b, wt, cq, bias1p, (float*)d_out);
}

// Round 14
// 168.347 us; speedup vs baseline: 1.0387x; 1.0019x over previous
//
#include <hip/hip_runtime.h>

typedef __bf16 bf16;
typedef short s16x8 __attribute__((ext_vector_type(8)));   // 8 bf16 bit-patterns for MFMA frags
typedef __bf16 b16x8 __attribute__((ext_vector_type(8)));  // 8 bf16 for scalar convert paths
typedef float f32x4 __attribute__((ext_vector_type(4)));

#define B_   4096
#define L_   50
#define SH   72               // H row stride (bf16): 64 + 8 pad

// ws layout, bf16 elems. Frag-major matrices: frag f = kt*4+nt is a contiguous
// 512-elem (1 KB) block; elem = f*512 + lane*8 + j -> W[k=kt*32+(lane>>4)*8+j][n=nt*16+(lane&15)].
// W2F/W3F/WCF/A2F (32 KB) staged to LDS by dense_fused; W1F stays global (L1-hot, verified R13).
#define OFF_W1F  0            // gv_w1  frag-major, K=128 (16 frags)
#define OFF_W2F  8192         // gv_w2  frag-major, K=64 (8 frags)
#define OFF_W3F  12288        // gv_w3  frag-major
#define OFF_WCF  16384        // (gv_w3 @ att_w1_top) frag-major
#define OFF_A2F  20480        // att_w2 frag-major
#define OFF_R1T  24576        // [64][128] wr1^T row-major (combine tail per-lane dots)
#define OFF_R2T  32768        // [64][64]  wr2^T row-major
#define WT_TOTAL 36864
// byte offsets in ws:
#define BIAS1P_BYTE 73728     // float[64]        att_b1 + gv_b3 @ att_w1_top
#define CQ_BYTE     73984     // float[4096][64]  q_b @ A1_bot  (bias1p added in dense)

#define PREP_W_BLOCKS 145     // ceil((WT_TOTAL+64)/256)
#define PREP_C_BLOCKS 1024    // 4096*64/256

__device__ __forceinline__ unsigned short f2b(float f) {
    __bf16 h = (__bf16)f;
    return __builtin_bit_cast(unsigned short, h);
}
__device__ __forceinline__ unsigned pack2(float a, float b) {
    return (unsigned)f2b(a) | ((unsigned)f2b(b) << 16);
}
__device__ __forceinline__ s16x8 mkfrag(float4 a, float4 b) {
    union { s16x8 v; unsigned u[4]; } r;
    r.u[0] = pack2(a.x, a.y); r.u[1] = pack2(a.z, a.w);
    r.u[2] = pack2(b.x, b.y); r.u[3] = pack2(b.z, b.w);
    return r.v;
}
__device__ __forceinline__ f32x4 mfma16(s16x8 a, s16x8 b, f32x4 c) {
    return __builtin_amdgcn_mfma_f32_16x16x32_bf16(a, b, c, 0, 0, 0);
}

// ---------------- prep (single launch): frag-major weights + bias1' + per-item cq ----------------
extern "C" __global__ void prep_all(const float* __restrict__ w1, const float* __restrict__ w2,
                                    const float* __restrict__ w3, const float* __restrict__ a1,
                                    const float* __restrict__ a2, const float* __restrict__ r1,
                                    const float* __restrict__ r2, const float* __restrict__ gb3,
                                    const float* __restrict__ ab1,
                                    const int* __restrict__ nodes_v, const float* __restrict__ embed_i,
                                    bf16* __restrict__ wt, float* __restrict__ bias1p,
                                    float* __restrict__ cq)
{
    if (blockIdx.x >= PREP_W_BLOCKS) {
        // cq[b][n] = q_b @ A1_bot   (bias1p added in dense)
        int gid = (blockIdx.x - PREP_W_BLOCKS) * 256 + threadIdx.x;   // 4096*64
        int b = gid >> 6, n = gid & 63;
        int v = nodes_v[b];
        const float* q = embed_i + v * 64;
        float s0 = 0.f, s1 = 0.f, s2 = 0.f, s3 = 0.f;
#pragma unroll
        for (int k = 0; k < 64; k += 4) {
            s0 = fmaf(q[k],     a1[(64 + k) * 64 + n],     s0);
            s1 = fmaf(q[k + 1], a1[(64 + k + 1) * 64 + n], s1);
            s2 = fmaf(q[k + 2], a1[(64 + k + 2) * 64 + n], s2);
            s3 = fmaf(q[k + 3], a1[(64 + k + 3) * 64 + n], s3);
        }
        cq[gid] = (s0 + s1) + (s2 + s3);
        return;
    }
    int i = blockIdx.x * 256 + threadIdx.x;
    if (i >= WT_TOTAL + 64) return;
    if (i >= WT_TOTAL) {                       // bias1'[n] = ab1[n] + sum_t gb3[t]*a1[t][n]
        int n = i - WT_TOTAL;
        float s0 = ab1[n], s1 = 0.f, s2 = 0.f, s3 = 0.f;
#pragma unroll
        for (int t = 0; t < 64; t += 4) {
            s0 = fmaf(gb3[t],     a1[t * 64 + n],       s0);
            s1 = fmaf(gb3[t + 1], a1[(t + 1) * 64 + n], s1);
            s2 = fmaf(gb3[t + 2], a1[(t + 2) * 64 + n], s2);
            s3 = fmaf(gb3[t + 3], a1[(t + 3) * 64 + n], s3);
        }
        bias1p[n] = (s0 + s1) + (s2 + s3);
        return;
    }
    float val;
    if (i < OFF_R1T) {
        int off, kind;   // 0=w1,1=w2,2=w3,3=wca,4=a2
        if      (i < OFF_W2F) { off = OFF_W1F; kind = 0; }
        else if (i < OFF_W3F) { off = OFF_W2F; kind = 1; }
        else if (i < OFF_WCF) { off = OFF_W3F; kind = 2; }
        else if (i < OFF_A2F) { off = OFF_WCF; kind = 3; }
        else                  { off = OFF_A2F; kind = 4; }
        int local = i - off;
        int f = local >> 9, lane = (local >> 3) & 63, j = local & 7;
        int kt = f >> 2, nt = f & 3, quad = lane >> 4, m = lane & 15;
        int k = kt * 32 + quad * 8 + j;
        int n = nt * 16 + m;
        if (kind == 0)      val = w1[k * 64 + n];
        else if (kind == 1) val = w2[k * 64 + n];
        else if (kind == 2) val = w3[k * 64 + n];
        else if (kind == 4) val = a2[k * 64 + n];
        else {                                  // wca[k][n] = (W3 @ A1_top)[k][n]
            float s0 = 0.f, s1 = 0.f, s2 = 0.f, s3 = 0.f;
#pragma unroll
            for (int t = 0; t < 64; t += 4) {
                float4 w = *(const float4*)(w3 + k * 64 + t);
                s0 = fmaf(w.x, a1[t * 64 + n],       s0);
                s1 = fmaf(w.y, a1[(t + 1) * 64 + n], s1);
                s2 = fmaf(w.z, a1[(t + 2) * 64 + n], s2);
                s3 = fmaf(w.w, a1[(t + 3) * 64 + n], s3);
            }
            val = (s0 + s1) + (s2 + s3);
        }
    }
    else if (i < OFF_R2T) { int li = i - OFF_R1T; int n = li >> 7, k = li & 127; val = r1[k * 64 + n]; }
    else                  { int li = i - OFF_R2T; int n = li >> 6, k = li & 63;  val = r2[k * 64 + n]; }
    wt[i] = (bf16)val;
}

// ---------------- fused: 512 threads = 8 single-tile waves; 2 items x 64 rows per block ----------------
// Wave w (0..7): item = w>>2, rows lbase=(w&3)*16 .. +16. K=64 weights in LDS (staged once,
// amortized over 8 waves); W1 global L1-hot. Single-tile regs (R11 footprint) + LDS B-supply (R13).
// LDS 52.7 KB (zp overlaid on dead H) -> 3 blocks/CU x 8 waves = 24 waves/CU cap.
extern "C" __global__ void __launch_bounds__(512, 2)
dense_fused(const int* __restrict__ nodes_v, const int* __restrict__ neigh_u,
            const int* __restrict__ neigh_r,
            const float* __restrict__ embed_u, const float* __restrict__ embed_i,
            const float* __restrict__ embed_r,
            const float* __restrict__ gv_b1, const float* __restrict__ gv_b2,
            const float* __restrict__ gv_b3,
            const float* __restrict__ att_b2, const float* __restrict__ att_w3,
            const float* __restrict__ wr1_b, const float* __restrict__ wr2_b,
            const bf16* __restrict__ wt, const float* __restrict__ cq,
            const float* __restrict__ bias1p, float* __restrict__ out)
{
    __shared__ __align__(16) bf16 Ws[16384];        // 32 KB: W2F|W3F|WCF|A2F frag-major
    __shared__ __align__(16) bf16 H[128 * SH];      // 18.4 KB: h1->h2->att1h; zp overlays after att2
    __shared__ float csS[128];                      // att1 bias per item (2 x 64)
    __shared__ float qsh[128];                      // q per item
    __shared__ float scs[128];                      // scores; reused as zj-share in tail
    float* zp = (float*)H;                          // 8x64 zj partials (H dead when written)

    const int tid = threadIdx.x;
    const int lane = tid & 63, wave = tid >> 6;     // 8 waves
    const int m = lane & 15, quad = lane >> 4;
    const int b0 = blockIdx.x * 2;
    const int item_w = wave >> 2;                   // waves 0-3 -> item 0, 4-7 -> item 1
    const int lbase = (wave & 3) * 16;              // this wave's 16 neighbor rows

    // ---- stage K=64 weights -> LDS (2048 uint4 by 512 threads; hidden behind gather+gv1) ----
    {
        const uint4* src = (const uint4*)(wt + OFF_W2F);
        uint4* dst = (uint4*)Ws;
#pragma unroll
        for (int it = 0; it < 4; ++it) dst[tid + it * 512] = src[tid + it * 512];
    }
    // stage per-item att1 bias (cq + bias1p) and q
    if (tid < 128) {
        int item = tid >> 6, n = tid & 63;
        csS[tid] = cq[(b0 + item) * 64 + n] + bias1p[n];
        qsh[tid] = embed_i[nodes_v[b0 + item] * 64 + n];
    }

    // this lane's neighbor row (clamped; pad rows masked at softmax)
    const int bw = b0 + item_w;
    const int l = min(lbase + m, L_ - 1);
    const int u = neigh_u[bw * L_ + l];
    const int r = neigh_r[bw * L_ + l];

    bf16* Hw = H + (item_w * 64 + lbase) * SH;      // this wave's 16 rows

    // ---- gv1 straight from global regs: h1 = relu([pt|er] @ W1 + b1) -> H (W1 from L1) ----
    {
        const float* pu = embed_u + u * 64;   // kt 0,1
        const float* pr = embed_r + r * 64;   // kt 2,3
        f32x4 ac[4] = {};
#pragma unroll
        for (int kt = 0; kt < 4; ++kt) {
            const float* sp = (kt < 2 ? pu : pr) + (kt & 1) * 32 + quad * 8;
            float4 aa = *(const float4*)sp, ab = *(const float4*)(sp + 4);
            s16x8 af = mkfrag(aa, ab);
#pragma unroll
            for (int nt = 0; nt < 4; ++nt) {
                s16x8 bw_ = *(const s16x8*)(wt + OFF_W1F + (kt * 4 + nt) * 512 + lane * 8);
                ac[nt] = mfma16(af, bw_, ac[nt]);
            }
        }
#pragma unroll
        for (int nt = 0; nt < 4; ++nt) {
            int c = nt * 16 + m;
            float bv = gv_b1[c];
#pragma unroll
            for (int r4 = 0; r4 < 4; ++r4)
                Hw[(quad * 4 + r4) * SH + c] = (bf16)fmaxf(ac[nt][r4] + bv, 0.f);
        }
    }

    __syncthreads();   // Ws + csS + qsh ready

    // ---- gv2: h1 -> h2 (in-place, same-wave WAR safe; B-frags from LDS) ----
    {
        f32x4 ac[4] = {};
#pragma unroll
        for (int kt = 0; kt < 2; ++kt) {
            s16x8 a = *(const s16x8*)(Hw + m * SH + kt * 32 + quad * 8);
#pragma unroll
            for (int nt = 0; nt < 4; ++nt) {
                s16x8 b = *(const s16x8*)(Ws + (kt * 4 + nt) * 512 + lane * 8);   // W2F
                ac[nt] = mfma16(a, b, ac[nt]);
            }
        }
#pragma unroll
        for (int nt = 0; nt < 4; ++nt) {
            int c = nt * 16 + m;
            float bv = gv_b2[c];
#pragma unroll
            for (int r4 = 0; r4 < 4; ++r4)
                Hw[(quad * 4 + r4) * SH + c] = (bf16)fmaxf(ac[nt][r4] + bv, 0.f);
        }
    }

    // ---- fused gv3 + att1': consume h2; fjt stays in regs (aF), att1h -> H ----
    f32x4 aF[4] = {};
    {
        f32x4 aA[4] = {};
#pragma unroll
        for (int kt = 0; kt < 2; ++kt) {
            s16x8 a = *(const s16x8*)(Hw + m * SH + kt * 32 + quad * 8);
#pragma unroll
            for (int nt = 0; nt < 4; ++nt) {
                s16x8 bF = *(const s16x8*)(Ws + 4096 + (kt * 4 + nt) * 512 + lane * 8);  // W3F
                s16x8 bA = *(const s16x8*)(Ws + 8192 + (kt * 4 + nt) * 512 + lane * 8);  // WCF
                aF[nt] = mfma16(a, bF, aF[nt]);
                aA[nt] = mfma16(a, bA, aA[nt]);
            }
        }
        // write only att1h; aF kept in regs (gv_b3 folded into zj via sum(mu)==1)
#pragma unroll
        for (int nt = 0; nt < 4; ++nt) {
            int c = nt * 16 + m;
            float b1v = csS[item_w * 64 + c];
#pragma unroll
            for (int r4 = 0; r4 < 4; ++r4)
                Hw[(quad * 4 + r4) * SH + c] = (bf16)fmaxf(aA[nt][r4] + b1v, 0.f);
        }
    }

    // ---- att2 + relu + dot(att_w3) + cross-m reduce -> scores (LDS) ----
    {
        f32x4 ac[4] = {};
#pragma unroll
        for (int kt = 0; kt < 2; ++kt) {
            s16x8 a = *(const s16x8*)(Hw + m * SH + kt * 32 + quad * 8);
#pragma unroll
            for (int nt = 0; nt < 4; ++nt) {
                s16x8 b = *(const s16x8*)(Ws + 12288 + (kt * 4 + nt) * 512 + lane * 8);  // A2F
                ac[nt] = mfma16(a, b, ac[nt]);
            }
        }
        float sc[4] = {0.f, 0.f, 0.f, 0.f};
#pragma unroll
        for (int nt = 0; nt < 4; ++nt) {
            int c = nt * 16 + m;
            float b2v = att_b2[c], w3v = att_w3[c];
#pragma unroll
            for (int r4 = 0; r4 < 4; ++r4)
                sc[r4] += fmaxf(ac[nt][r4] + b2v, 0.f) * w3v;
        }
#pragma unroll
        for (int mask = 1; mask < 16; mask <<= 1)
#pragma unroll
            for (int r4 = 0; r4 < 4; ++r4) sc[r4] += __shfl_xor(sc[r4], mask);
        if (m == 0) {
#pragma unroll
            for (int r4 = 0; r4 < 4; ++r4)
                scs[item_w * 64 + lbase + quad * 4 + r4] = sc[r4];
        }
    }
    __syncthreads();   // scores ready; all H reads done -> zp may overlay H

    // ---- per-wave softmax + zj from aF regs ----
    {
        float s = (lane < L_) ? scs[item_w * 64 + lane] : -1e30f;
        float mx = s;
#pragma unroll
        for (int off = 32; off; off >>= 1) mx = fmaxf(mx, __shfl_xor(mx, off));
        float e = (lane < L_) ? __expf(s - mx) : 0.f;
        float sum = e;
#pragma unroll
        for (int off = 32; off; off >>= 1) sum += __shfl_xor(sum, off);
        float mu = e / sum;   // mu[lane] of this wave's item

        float z[4] = {0.f, 0.f, 0.f, 0.f};
#pragma unroll
        for (int r4 = 0; r4 < 4; ++r4) {
            float mr = __shfl(mu, lbase + quad * 4 + r4);
#pragma unroll
            for (int nt = 0; nt < 4; ++nt) z[nt] += aF[nt][r4] * mr;
        }
#pragma unroll
        for (int nt = 0; nt < 4; ++nt) {
            z[nt] += __shfl_xor(z[nt], 16);
            z[nt] += __shfl_xor(z[nt], 32);
        }
        if (quad == 0) {
#pragma unroll
            for (int nt = 0; nt < 4; ++nt) zp[wave * 64 + nt * 16 + m] = z[nt];
        }
    }
    __syncthreads();

    // ---- combine tail: wave 0 -> item 0, wave 4 -> item 1 ----
    if ((wave & 3) == 0) {
        const int item = wave >> 2;
        const int d = lane;
        float z = zp[(wave + 0) * 64 + d] + zp[(wave + 1) * 64 + d]
                + zp[(wave + 2) * 64 + d] + zp[(wave + 3) * 64 + d] + gv_b3[d];
        float* zsh = scs + item * 64;   // scores dead; reuse (same-wave in-order)
        zsh[d] = z;

        // z2 = relu([zj|q] @ wr1 + b1)
        float accz = wr1_b[d];
        const bf16* r1 = wt + OFF_R1T + d * 128;
#pragma unroll
        for (int k8 = 0; k8 < 8; ++k8) {
            b16x8 wv = *(const b16x8*)(r1 + k8 * 8);
#pragma unroll
            for (int j = 0; j < 8; ++j) accz = fmaf((float)wv[j], zsh[k8 * 8 + j], accz);
        }
#pragma unroll
        for (int k8 = 0; k8 < 8; ++k8) {
            b16x8 wv = *(const b16x8*)(r1 + 64 + k8 * 8);
#pragma unroll
            for (int j = 0; j < 8; ++j) accz = fmaf((float)wv[j], qsh[item * 64 + k8 * 8 + j], accz);
        }
        float* z2sh = zp + wave * 64;   // reuse own partial slot (same-wave in-order)
        z2sh[d] = fmaxf(accz, 0.f);

        // out = relu(z2 @ wr2 + b2)
        float acco = wr2_b[d];
        const bf16* r2 = wt + OFF_R2T + d * 64;
#pragma unroll
        for (int k8 = 0; k8 < 8; ++k8) {
            b16x8 wv = *(const b16x8*)(r2 + k8 * 8);
#pragma unroll
            for (int j = 0; j < 8; ++j) acco = fmaf((float)wv[j], z2sh[k8 * 8 + j], acco);
        }
        out[(b0 + item) * 64 + d] = fmaxf(acco, 0.f);
    }
}

extern "C" void kernel_launch(void* const* d_in, const int* in_sizes, int n_in,
                              void* d_out, int out_size, void* d_ws, size_t ws_size,
                              hipStream_t stream)
{
    const int* nodes_v = (const int*)d_in[0];
    const int* neigh_u = (const int*)d_in[1];
    const int* neigh_r = (const int*)d_in[2];
    const float* embed_u = (const float*)d_in[3];
    const float* embed_i = (const float*)d_in[4];
    const float* embed_r = (const float*)d_in[5];
    const float* gv_w1  = (const float*)d_in[6];  const float* gv_b1 = (const float*)d_in[7];
    const float* gv_w2  = (const float*)d_in[8];  const float* gv_b2 = (const float*)d_in[9];
    const float* gv_w3  = (const float*)d_in[10]; const float* gv_b3 = (const float*)d_in[11];
    const float* att_w1 = (const float*)d_in[12]; const float* att_b1 = (const float*)d_in[13];
    const float* att_w2 = (const float*)d_in[14]; const float* att_b2 = (const float*)d_in[15];
    const float* att_w3 = (const float*)d_in[16]; const float* att_b3 = (const float*)d_in[17];
    const float* wr1_w  = (const float*)d_in[18]; const float* wr1_b = (const float*)d_in[19];
    const float* wr2_w  = (const float*)d_in[20]; const float* wr2_b = (const float*)d_in[21];
    (void)att_b3;  // softmax shift-invariance

    bf16*  wt     = (bf16*)d_ws;
    float* bias1p = (float*)((char*)d_ws + BIAS1P_BYTE);
    float* cq     = (float*)((char*)d_ws + CQ_BYTE);

    prep_all<<<PREP_W_BLOCKS + PREP_C_BLOCKS, 256, 0, stream>>>(
        gv_w1, gv_w2, gv_w3, att_w1, att_w2, wr1_w, wr2_w, gv_b3, att_b1,
        nodes_v, embed_i, wt, bias1p, cq);
    dense_fused<<<B_ / 2, 512, 0, stream>>>(nodes_v, neigh_u, neigh_r,
                                            embed_u, embed_i, embed_r,
                                            gv_b1, gv_b2, gv_b3, att_b2, att_w3,
                                            wr1_b, wr2_b, wt, cq, bias1p, (float*)d_out);
}

// Round 15
// 167.459 us; speedup vs baseline: 1.0442x; 1.0053x over previous
//
#include <hip/hip_runtime.h>

typedef __bf16 bf16;
typedef short s16x8 __attribute__((ext_vector_type(8)));   // 8 bf16 bit-patterns for MFMA frags
typedef __bf16 b16x8 __attribute__((ext_vector_type(8)));  // 8 bf16 for scalar convert paths
typedef float f32x4 __attribute__((ext_vector_type(4)));

#define B_   4096
#define L_   50
#define SH   72               // H row stride (bf16): 64 + 8 pad (2-way bank alias, free)

// ws layout, bf16 elems. Frag-major matrices: frag f = kt*4+nt is a contiguous
// 512-elem (1 KB) block; elem = f*512 + lane*8 + j -> W[k=kt*32+(lane>>4)*8+j][n=nt*16+(lane&15)].
#define OFF_W1F  0            // gv_w1  frag-major, K=128 (16 frags)
#define OFF_W2F  8192         // gv_w2  frag-major, K=64 (8 frags)
#define OFF_W3F  12288        // gv_w3  frag-major
#define OFF_WCF  16384        // (gv_w3 @ att_w1_top) frag-major
#define OFF_A2F  20480        // att_w2 frag-major
#define OFF_R1T  24576        // [64][128] wr1^T row-major (combine tail per-lane dots)
#define OFF_R2T  32768        // [64][64]  wr2^T row-major
#define WT_TOTAL 36864
// byte offsets in ws:
#define BIAS1P_BYTE 73728     // float[64]        att_b1 + gv_b3 @ att_w1_top
#define CQ_BYTE     73984     // float[4096][64]  q_b @ A1_bot  (bias1p added in dense)

#define PREP_W_BLOCKS 145     // ceil((WT_TOTAL+64)/256)
#define PREP_C_BLOCKS 1024    // 4096*64/256

__device__ __forceinline__ unsigned short f2b(float f) {
    __bf16 h = (__bf16)f;
    return __builtin_bit_cast(unsigned short, h);
}
__device__ __forceinline__ unsigned pack2(float a, float b) {
    return (unsigned)f2b(a) | ((unsigned)f2b(b) << 16);
}
__device__ __forceinline__ s16x8 mkfrag(float4 a, float4 b) {
    union { s16x8 v; unsigned u[4]; } r;
    r.u[0] = pack2(a.x, a.y); r.u[1] = pack2(a.z, a.w);
    r.u[2] = pack2(b.x, b.y); r.u[3] = pack2(b.z, b.w);
    return r.v;
}
__device__ __forceinline__ f32x4 mfma16(s16x8 a, s16x8 b, f32x4 c) {
    return __builtin_amdgcn_mfma_f32_16x16x32_bf16(a, b, c, 0, 0, 0);
}

// ---------------- prep (single launch): frag-major weights + bias1' + per-item cq ----------------
extern "C" __global__ void prep_all(const float* __restrict__ w1, const float* __restrict__ w2,
                                    const float* __restrict__ w3, const float* __restrict__ a1,
                                    const float* __restrict__ a2, const float* __restrict__ r1,
                                    const float* __restrict__ r2, const float* __restrict__ gb3,
                                    const float* __restrict__ ab1,
                                    const int* __restrict__ nodes_v, const float* __restrict__ embed_i,
                                    bf16* __restrict__ wt, float* __restrict__ bias1p,
                                    float* __restrict__ cq)
{
    if (blockIdx.x >= PREP_W_BLOCKS) {
        // cq[b][n] = q_b @ A1_bot   (bias1p added in dense)
        int gid = (blockIdx.x - PREP_W_BLOCKS) * 256 + threadIdx.x;   // 4096*64
        int b = gid >> 6, n = gid & 63;
        int v = nodes_v[b];
        const float* q = embed_i + v * 64;
        float s0 = 0.f, s1 = 0.f, s2 = 0.f, s3 = 0.f;
#pragma unroll
        for (int k = 0; k < 64; k += 4) {
            s0 = fmaf(q[k],     a1[(64 + k) * 64 + n],     s0);
            s1 = fmaf(q[k + 1], a1[(64 + k + 1) * 64 + n], s1);
            s2 = fmaf(q[k + 2], a1[(64 + k + 2) * 64 + n], s2);
            s3 = fmaf(q[k + 3], a1[(64 + k + 3) * 64 + n], s3);
        }
        cq[gid] = (s0 + s1) + (s2 + s3);
        return;
    }
    int i = blockIdx.x * 256 + threadIdx.x;
    if (i >= WT_TOTAL + 64) return;
    if (i >= WT_TOTAL) {                       // bias1'[n] = ab1[n] + sum_t gb3[t]*a1[t][n]
        int n = i - WT_TOTAL;
        float s0 = ab1[n], s1 = 0.f, s2 = 0.f, s3 = 0.f;
#pragma unroll
        for (int t = 0; t < 64; t += 4) {
            s0 = fmaf(gb3[t],     a1[t * 64 + n],       s0);
            s1 = fmaf(gb3[t + 1], a1[(t + 1) * 64 + n], s1);
            s2 = fmaf(gb3[t + 2], a1[(t + 2) * 64 + n], s2);
            s3 = fmaf(gb3[t + 3], a1[(t + 3) * 64 + n], s3);
        }
        bias1p[n] = (s0 + s1) + (s2 + s3);
        return;
    }
    float val;
    if (i < OFF_R1T) {
        int off, kind;   // 0=w1,1=w2,2=w3,3=wca,4=a2
        if      (i < OFF_W2F) { off = OFF_W1F; kind = 0; }
        else if (i < OFF_W3F) { off = OFF_W2F; kind = 1; }
        else if (i < OFF_WCF) { off = OFF_W3F; kind = 2; }
        else if (i < OFF_A2F) { off = OFF_WCF; kind = 3; }
        else                  { off = OFF_A2F; kind = 4; }
        int local = i - off;
        int f = local >> 9, lane = (local >> 3) & 63, j = local & 7;
        int kt = f >> 2, nt = f & 3, quad = lane >> 4, m = lane & 15;
        int k = kt * 32 + quad * 8 + j;
        int n = nt * 16 + m;
        if (kind == 0)      val = w1[k * 64 + n];
        else if (kind == 1) val = w2[k * 64 + n];
        else if (kind == 2) val = w3[k * 64 + n];
        else if (kind == 4) val = a2[k * 64 + n];
        else {                                  // wca[k][n] = (W3 @ A1_top)[k][n]
            float s0 = 0.f, s1 = 0.f, s2 = 0.f, s3 = 0.f;
#pragma unroll
            for (int t = 0; t < 64; t += 4) {
                float4 w = *(const float4*)(w3 + k * 64 + t);
                s0 = fmaf(w.x, a1[t * 64 + n],       s0);
                s1 = fmaf(w.y, a1[(t + 1) * 64 + n], s1);
                s2 = fmaf(w.z, a1[(t + 2) * 64 + n], s2);
                s3 = fmaf(w.w, a1[(t + 3) * 64 + n], s3);
            }
            val = (s0 + s1) + (s2 + s3);
        }
    }
    else if (i < OFF_R2T) { int li = i - OFF_R1T; int n = li >> 7, k = li & 127; val = r1[k * 64 + n]; }
    else                  { int li = i - OFF_R2T; int n = li >> 6, k = li & 63;  val = r2[k * 64 + n]; }
    wt[i] = (bf16)val;
}

// ---------------- fused: 2 items x 64 rows/block, dual-tile waves, ONE barrier ----------------
// R10 structure (best measured) with barriers 3->1: att1-bias via per-lane global loads (no
// staging barrier); per-wave ONLINE-softmax partials (local max/sum/e-weighted fjt-sum from aF
// regs) merged in the tail -> scores never cross waves before the single pre-tail barrier.
extern "C" __global__ void __launch_bounds__(256, 2)
dense_fused(const int* __restrict__ nodes_v, const int* __restrict__ neigh_u,
            const int* __restrict__ neigh_r,
            const float* __restrict__ embed_u, const float* __restrict__ embed_i,
            const float* __restrict__ embed_r,
            const float* __restrict__ gv_b1, const float* __restrict__ gv_b2,
            const float* __restrict__ gv_b3,
            const float* __restrict__ att_b2, const float* __restrict__ att_w3,
            const float* __restrict__ wr1_b, const float* __restrict__ wr2_b,
            const bf16* __restrict__ wt, const float* __restrict__ cq,
            const float* __restrict__ bias1p, float* __restrict__ out)
{
    __shared__ __align__(16) bf16 H[128 * SH];      // 18.4 KB: h1 -> h2 -> att1h (same-wave reuse)
    __shared__ float zp[4 * 64];                    // per-wave e-weighted fjt partial S_w[64]
    __shared__ float swm[4 * 2];                    // per-wave {sum_e, max}
    __shared__ float qsh[2 * 64];                   // q per item (staged by tail wave)

    const int tid = threadIdx.x;
    const int lane = tid & 63, wave = tid >> 6;
    const int m = lane & 15, quad = lane >> 4;
    const int b0 = blockIdx.x * 2;
    const int rw0 = wave * 32;                      // wave's rows in [0,128)
    const int item_w = rw0 >> 6;                    // this wave's item (0/1)
    const int lbase = rw0 & 63;                     // neighbor offset within item (0/32)

    // neighbor indices for this lane's two A-frag rows (clamped; pad rows masked at softmax)
    const int bw = b0 + item_w;
    const int l0 = min(lbase + m, L_ - 1);
    const int l1 = min(lbase + 16 + m, L_ - 1);
    const int u0 = neigh_u[bw * L_ + l0], u1 = neigh_u[bw * L_ + l1];
    const int v0 = neigh_r[bw * L_ + l0], v1 = neigh_r[bw * L_ + l1];

    // att1 per-item bias, per-lane (replaces LDS staging + barrier); hoisted early, L1/L2-hot
    float cs4[4];
#pragma unroll
    for (int nt = 0; nt < 4; ++nt) {
        int c = nt * 16 + m;
        cs4[nt] = cq[bw * 64 + c] + bias1p[c];
    }

    bf16* Hw = H + rw0 * SH;   // this wave's 32 rows
    bf16* H0 = Hw;             // tile 0
    bf16* H1 = Hw + 16 * SH;   // tile 1

    // ---- gv1 straight from global regs: h1 = relu([pt|er] @ W1 + b1) -> H ----
    {
        const float* b00 = embed_u + u0 * 64;   // kt 0,1: pt
        const float* b01 = embed_u + u1 * 64;
        const float* b10 = embed_r + v0 * 64;   // kt 2,3: er
        const float* b11 = embed_r + v1 * 64;
        f32x4 ac0[4] = {}, ac1[4] = {};
#pragma unroll
        for (int kt = 0; kt < 4; ++kt) {
            const float* s0p = (kt < 2 ? b00 : b10) + (kt & 1) * 32 + quad * 8;
            const float* s1p = (kt < 2 ? b01 : b11) + (kt & 1) * 32 + quad * 8;
            float4 a0a = *(const float4*)s0p, a0b = *(const float4*)(s0p + 4);
            float4 a1a = *(const float4*)s1p, a1b = *(const float4*)(s1p + 4);
            s16x8 a0 = mkfrag(a0a, a0b);
            s16x8 a1 = mkfrag(a1a, a1b);
#pragma unroll
            for (int nt = 0; nt < 4; ++nt) {
                s16x8 b = *(const s16x8*)(wt + OFF_W1F + (kt * 4 + nt) * 512 + lane * 8);
                ac0[nt] = mfma16(a0, b, ac0[nt]);
                ac1[nt] = mfma16(a1, b, ac1[nt]);
            }
        }
#pragma unroll
        for (int nt = 0; nt < 4; ++nt) {
            int c = nt * 16 + m;
            float bv = gv_b1[c];
#pragma unroll
            for (int r4 = 0; r4 < 4; ++r4) {
                H0[(quad * 4 + r4) * SH + c] = (bf16)fmaxf(ac0[nt][r4] + bv, 0.f);
                H1[(quad * 4 + r4) * SH + c] = (bf16)fmaxf(ac1[nt][r4] + bv, 0.f);
            }
        }
    }

    // ---- gv2: h1 -> h2 (in-place, same-wave WAR safe) ----
    {
        f32x4 ac0[4] = {}, ac1[4] = {};
#pragma unroll
        for (int kt = 0; kt < 2; ++kt) {
            s16x8 a0 = *(const s16x8*)(H0 + m * SH + kt * 32 + quad * 8);
            s16x8 a1 = *(const s16x8*)(H1 + m * SH + kt * 32 + quad * 8);
#pragma unroll
            for (int nt = 0; nt < 4; ++nt) {
                s16x8 b = *(const s16x8*)(wt + OFF_W2F + (kt * 4 + nt) * 512 + lane * 8);
                ac0[nt] = mfma16(a0, b, ac0[nt]);
                ac1[nt] = mfma16(a1, b, ac1[nt]);
            }
        }
#pragma unroll
        for (int nt = 0; nt < 4; ++nt) {
            int c = nt * 16 + m;
            float bv = gv_b2[c];
#pragma unroll
            for (int r4 = 0; r4 < 4; ++r4) {
                H0[(quad * 4 + r4) * SH + c] = (bf16)fmaxf(ac0[nt][r4] + bv, 0.f);
                H1[(quad * 4 + r4) * SH + c] = (bf16)fmaxf(ac1[nt][r4] + bv, 0.f);
            }
        }
    }

    // ---- fused gv3 + att1': consume h2; fjt stays in regs (aF), att1h -> H ----
    f32x4 aF0[4] = {}, aF1[4] = {};
    {
        f32x4 aA0[4] = {}, aA1[4] = {};
#pragma unroll
        for (int kt = 0; kt < 2; ++kt) {
            s16x8 a0 = *(const s16x8*)(H0 + m * SH + kt * 32 + quad * 8);
            s16x8 a1 = *(const s16x8*)(H1 + m * SH + kt * 32 + quad * 8);
#pragma unroll
            for (int nt = 0; nt < 4; ++nt) {
                s16x8 bF = *(const s16x8*)(wt + OFF_W3F + (kt * 4 + nt) * 512 + lane * 8);
                s16x8 bA = *(const s16x8*)(wt + OFF_WCF + (kt * 4 + nt) * 512 + lane * 8);
                aF0[nt] = mfma16(a0, bF, aF0[nt]);
                aF1[nt] = mfma16(a1, bF, aF1[nt]);
                aA0[nt] = mfma16(a0, bA, aA0[nt]);
                aA1[nt] = mfma16(a1, bA, aA1[nt]);
            }
        }
        // write only att1h; aF kept in regs (gv_b3 folded into zj via sum(mu)==1)
#pragma unroll
        for (int nt = 0; nt < 4; ++nt) {
            int c = nt * 16 + m;
#pragma unroll
            for (int r4 = 0; r4 < 4; ++r4) {
                H0[(quad * 4 + r4) * SH + c] = (bf16)fmaxf(aA0[nt][r4] + cs4[nt], 0.f);
                H1[(quad * 4 + r4) * SH + c] = (bf16)fmaxf(aA1[nt][r4] + cs4[nt], 0.f);
            }
        }
    }

    // ---- att2 + relu + dot(att_w3) + m-reduce -> per-row scores in regs ----
    float s0[4], s1[4];
    {
        f32x4 ac0[4] = {}, ac1[4] = {};
#pragma unroll
        for (int kt = 0; kt < 2; ++kt) {
            s16x8 a0 = *(const s16x8*)(H0 + m * SH + kt * 32 + quad * 8);
            s16x8 a1 = *(const s16x8*)(H1 + m * SH + kt * 32 + quad * 8);
#pragma unroll
            for (int nt = 0; nt < 4; ++nt) {
                s16x8 b = *(const s16x8*)(wt + OFF_A2F + (kt * 4 + nt) * 512 + lane * 8);
                ac0[nt] = mfma16(a0, b, ac0[nt]);
                ac1[nt] = mfma16(a1, b, ac1[nt]);
            }
        }
#pragma unroll
        for (int r4 = 0; r4 < 4; ++r4) { s0[r4] = 0.f; s1[r4] = 0.f; }
#pragma unroll
        for (int nt = 0; nt < 4; ++nt) {
            int c = nt * 16 + m;
            float b2v = att_b2[c], w3v = att_w3[c];
#pragma unroll
            for (int r4 = 0; r4 < 4; ++r4) {
                s0[r4] += fmaxf(ac0[nt][r4] + b2v, 0.f) * w3v;
                s1[r4] += fmaxf(ac1[nt][r4] + b2v, 0.f) * w3v;
            }
        }
        // reduce across the 16 m-lanes (masks 1,2,4,8): scores become m-uniform per quad
#pragma unroll
        for (int mask = 1; mask < 16; mask <<= 1)
#pragma unroll
            for (int r4 = 0; r4 < 4; ++r4) {
                s0[r4] += __shfl_xor(s0[r4], mask);
                s1[r4] += __shfl_xor(s1[r4], mask);
            }
    }

    // ---- per-wave ONLINE-softmax partial over this wave's 32 rows (no cross-wave data) ----
    {
        // rows: tile0 = lbase + quad*4 + r4 ; tile1 = +16. Mask pad rows (>= L_).
        const int r0b = lbase + quad * 4;
        float mloc = -1e30f;
#pragma unroll
        for (int r4 = 0; r4 < 4; ++r4) {
            if (r0b + r4 < L_)      mloc = fmaxf(mloc, s0[r4]);
            if (r0b + 16 + r4 < L_) mloc = fmaxf(mloc, s1[r4]);
        }
        mloc = fmaxf(mloc, __shfl_xor(mloc, 16));
        mloc = fmaxf(mloc, __shfl_xor(mloc, 32));   // wave-local max (m-uniform already)

        float e0[4], e1[4], ssum = 0.f;
#pragma unroll
        for (int r4 = 0; r4 < 4; ++r4) {
            e0[r4] = (r0b + r4 < L_)      ? __expf(s0[r4] - mloc) : 0.f;
            e1[r4] = (r0b + 16 + r4 < L_) ? __expf(s1[r4] - mloc) : 0.f;
            ssum += e0[r4] + e1[r4];
        }
        ssum += __shfl_xor(ssum, 16);
        ssum += __shfl_xor(ssum, 32);

        float z[4] = {0.f, 0.f, 0.f, 0.f};
#pragma unroll
        for (int r4 = 0; r4 < 4; ++r4)
#pragma unroll
            for (int nt = 0; nt < 4; ++nt)
                z[nt] += aF0[nt][r4] * e0[r4] + aF1[nt][r4] * e1[r4];
#pragma unroll
        for (int nt = 0; nt < 4; ++nt) {
            z[nt] += __shfl_xor(z[nt], 16);
            z[nt] += __shfl_xor(z[nt], 32);
        }
        if (quad == 0) {
#pragma unroll
            for (int nt = 0; nt < 4; ++nt) zp[wave * 64 + nt * 16 + m] = z[nt];
        }
        if (lane == 0) { swm[wave * 2] = ssum; swm[wave * 2 + 1] = mloc; }
    }
    __syncthreads();   // the ONLY barrier

    // ---- tail: wave 0 -> item 0, wave 2 -> item 1 (online-softmax merge + combine) ----
    if ((wave & 1) == 0) {
        const int item = wave >> 1;
        const int d = lane;
        float ma = swm[wave * 2 + 1],      mb = swm[(wave + 1) * 2 + 1];
        float sa = swm[wave * 2],          sb = swm[(wave + 1) * 2];
        float M  = fmaxf(ma, mb);
        float fa = __expf(ma - M), fb = __expf(mb - M);
        float zj = (fa * zp[wave * 64 + d] + fb * zp[(wave + 1) * 64 + d])
                 / (fa * sa + fb * sb) + gv_b3[d];

        // share zj and q via LDS (same-wave in-order; zp[wave] slot is dead after the read above)
        float* zsh = zp + wave * 64;
        zsh[d] = zj;
        qsh[item * 64 + d] = embed_i[nodes_v[b0 + item] * 64 + d];

        // z2 = relu([zj|q] @ wr1 + b1)
        float accz = wr1_b[d];
        const bf16* r1 = wt + OFF_R1T + d * 128;
#pragma unroll
        for (int k8 = 0; k8 < 8; ++k8) {
            b16x8 wv = *(const b16x8*)(r1 + k8 * 8);
#pragma unroll
            for (int j = 0; j < 8; ++j) accz = fmaf((float)wv[j], zsh[k8 * 8 + j], accz);
        }
#pragma unroll
        for (int k8 = 0; k8 < 8; ++k8) {
            b16x8 wv = *(const b16x8*)(r1 + 64 + k8 * 8);
#pragma unroll
            for (int j = 0; j < 8; ++j) accz = fmaf((float)wv[j], qsh[item * 64 + k8 * 8 + j], accz);
        }
        zsh[d] = fmaxf(accz, 0.f);   // reuse as z2-share (same-wave in-order)

        // out = relu(z2 @ wr2 + b2)
        float acco = wr2_b[d];
        const bf16* r2 = wt + OFF_R2T + d * 64;
#pragma unroll
        for (int k8 = 0; k8 < 8; ++k8) {
            b16x8 wv = *(const b16x8*)(r2 + k8 * 8);
#pragma unroll
            for (int j = 0; j < 8; ++j) acco = fmaf((float)wv[j], zsh[k8 * 8 + j], acco);
        }
        out[(b0 + item) * 64 + d] = fmaxf(acco, 0.f);
    }
}

extern "C" void kernel_launch(void* const* d_in, const int* in_sizes, int n_in,
                              void* d_out, int out_size, void* d_ws, size_t ws_size,
                              hipStream_t stream)
{
    const int* nodes_v = (const int*)d_in[0];
    const int* neigh_u = (const int*)d_in[1];
    const int* neigh_r = (const int*)d_in[2];
    const float* embed_u = (const float*)d_in[3];
    const float* embed_i = (const float*)d_in[4];
    const float* embed_r = (const float*)d_in[5];
    const float* gv_w1  = (const float*)d_in[6];  const float* gv_b1 = (const float*)d_in[7];
    const float* gv_w2  = (const float*)d_in[8];  const float* gv_b2 = (const float*)d_in[9];
    const float* gv_w3  = (const float*)d_in[10]; const float* gv_b3 = (const float*)d_in[11];
    const float* att_w1 = (const float*)d_in[12]; const float* att_b1 = (const float*)d_in[13];
    const float* att_w2 = (const float*)d_in[14]; const float* att_b2 = (const float*)d_in[15];
    const float* att_w3 = (const float*)d_in[16]; const float* att_b3 = (const float*)d_in[17];
    const float* wr1_w  = (const float*)d_in[18]; const float* wr1_b = (const float*)d_in[19];
    const float* wr2_w  = (const float*)d_in[20]; const float* wr2_b = (const float*)d_in[21];
    (void)att_b3;  // softmax shift-invariance

    bf16*  wt     = (bf16*)d_ws;
    float* bias1p = (float*)((char*)d_ws + BIAS1P_BYTE);
    float* cq     = (float*)((char*)d_ws + CQ_BYTE);

    prep_all<<<PREP_W_BLOCKS + PREP_C_BLOCKS, 256, 0, stream>>>(
        gv_w1, gv_w2, gv_w3, att_w1, att_w2, wr1_w, wr2_w, gv_b3, att_b1,
        nodes_v, embed_i, wt, bias1p, cq);
    dense_fused<<<B_ / 2, 256, 0, stream>>>(nodes_v, neigh_u, neigh_r,
                                            embed_u, embed_i, embed_r,
                                            gv_b1, gv_b2, gv_b3, att_b2, att_w3,
                                            wr1_b, wr2_b, wt, cq, bias1p, (float*)d_out);
}